// Round 2
// baseline (6927.170 us; speedup 1.0000x reference)
//
#include <hip/hip_runtime.h>
#include <math.h>
#include <stdint.h>

// ---------------------------------------------------------------------------
// PointerNet, fully fused, workspace = EncOuts only (64 MiB).
//   enc_fused: 512 blocks x 512 thr, wih+whh in VGPRs, writes EncOuts.
//   dec_fused: 512 blocks x 256 thr, dec_wih+dec_whh+w2 in VGPRs,
//              w1e computed in-kernel into LDS, exact JAX threefry sampling.
// ---------------------------------------------------------------------------

#define RNG_PARTITIONABLE 1   // modern JAX: bits = o0 ^ o1 of tf(key,(0,i))

__device__ __forceinline__ uint32_t rotl32_(uint32_t v, int r){ return (v<<r)|(v>>(32-r)); }

// Threefry-2x32, 20 rounds, JAX's exact schedule.
__device__ __forceinline__ void tf2x32(uint32_t k0, uint32_t k1, uint32_t x0, uint32_t x1,
                                       uint32_t& o0, uint32_t& o1){
  uint32_t k2 = k0 ^ k1 ^ 0x1BD11BDAu;
  x0 += k0; x1 += k1;
  x0 += x1; x1 = rotl32_(x1,13); x1 ^= x0;
  x0 += x1; x1 = rotl32_(x1,15); x1 ^= x0;
  x0 += x1; x1 = rotl32_(x1,26); x1 ^= x0;
  x0 += x1; x1 = rotl32_(x1, 6); x1 ^= x0;
  x0 += k1; x1 += k2 + 1u;
  x0 += x1; x1 = rotl32_(x1,17); x1 ^= x0;
  x0 += x1; x1 = rotl32_(x1,29); x1 ^= x0;
  x0 += x1; x1 = rotl32_(x1,16); x1 ^= x0;
  x0 += x1; x1 = rotl32_(x1,24); x1 ^= x0;
  x0 += k2; x1 += k0 + 2u;
  x0 += x1; x1 = rotl32_(x1,13); x1 ^= x0;
  x0 += x1; x1 = rotl32_(x1,15); x1 ^= x0;
  x0 += x1; x1 = rotl32_(x1,26); x1 ^= x0;
  x0 += x1; x1 = rotl32_(x1, 6); x1 ^= x0;
  x0 += k0; x1 += k1 + 3u;
  x0 += x1; x1 = rotl32_(x1,17); x1 ^= x0;
  x0 += x1; x1 = rotl32_(x1,29); x1 ^= x0;
  x0 += x1; x1 = rotl32_(x1,16); x1 ^= x0;
  x0 += x1; x1 = rotl32_(x1,24); x1 ^= x0;
  x0 += k1; x1 += k2 + 4u;
  x0 += x1; x1 = rotl32_(x1,13); x1 ^= x0;
  x0 += x1; x1 = rotl32_(x1,15); x1 ^= x0;
  x0 += x1; x1 = rotl32_(x1,26); x1 ^= x0;
  x0 += x1; x1 = rotl32_(x1, 6); x1 ^= x0;
  x0 += k2; x1 += k0 + 5u;
  o0 = x0; o1 = x1;
}

// XLA f32 tanh: clamp [-9,9], rational poly, x for |x|<4e-4, IEEE div.
__device__ __forceinline__ float tanh_xla(float x){
#pragma clang fp contract(off)
  float xc = fminf(fmaxf(x, -9.0f), 9.0f);
  float x2 = xc*xc;
  float num = -2.76076847742355e-16f;
  num = x2*num + 2.00018790482477e-13f;
  num = x2*num + (-8.60467152213735e-11f);
  num = x2*num + 5.12229709037114e-08f;
  num = x2*num + 1.48572235717979e-05f;
  num = x2*num + 6.37261928875436e-04f;
  num = x2*num + 4.89352455891786e-03f;
  num = xc*num;
  float den = 1.19825839466702e-06f;
  den = x2*den + 1.18534705686654e-04f;
  den = x2*den + 2.26843463243900e-03f;
  den = x2*den + 4.89352518554385e-03f;
  float r = num/den;
  return (fabsf(x) < 4e-4f) ? x : r;
}

__device__ __forceinline__ float sigmoid_xla(float x){
  return 1.0f/(1.0f + expf(-x));
}

// --------------------------- Encoder, fully fused ---------------------------
__global__ __launch_bounds__(512,2) void enc_fused(
    const float* __restrict__ pts, const float* __restrict__ fcw, const float* __restrict__ fcb,
    const float* __restrict__ wih, const float* __restrict__ whh,
    const float* __restrict__ bih, const float* __restrict__ bhh,
    float* __restrict__ EncOuts)
{
  __shared__ float x_s[128], h_s[128], pGI[1536], pGH[1536], bih_s[384], bhh_s[384];
  const int tid = threadIdx.x, b = blockIdx.x;
  const int hg = tid >> 7, c = tid & 127;
  float wi0[32],wi1[32],wi2[32],wh0[32],wh1[32],wh2[32];
  #pragma unroll
  for (int i=0;i<32;++i){
    int row = (hg*32+i)*384;
    wi0[i]=wih[row+c]; wi1[i]=wih[row+128+c]; wi2[i]=wih[row+256+c];
    wh0[i]=whh[row+c]; wh1[i]=whh[row+128+c]; wh2[i]=whh[row+256+c];
  }
  if (tid<384){ bih_s[tid]=bih[tid]; bhh_s[tid]=bhh[tid]; }
  float fw0=0.f,fw1=0.f,fb=0.f;
  if (tid<128){
#pragma clang fp contract(off)
    fw0=fcw[c]; fw1=fcw[128+c]; fb=fcb[c];
    h_s[c]=0.f;
    float p0=pts[(size_t)b*512], p1=pts[(size_t)b*512+1];
    float v = fmaf(p1,fw1,p0*fw0)+fb;
    x_s[c]=fmaxf(v,0.f);
  }
  __syncthreads();
  for (int t=0;t<256;++t){
    float a0=0,a1=0,a2=0,g0=0,g1=0,g2=0;
    const float4* x4=(const float4*)&x_s[hg*32];
    const float4* h4=(const float4*)&h_s[hg*32];
    #pragma unroll
    for (int i4=0;i4<8;++i4){
      float4 xv=x4[i4], hv=h4[i4];
      const int i=i4*4;
      a0=fmaf(xv.x,wi0[i  ],a0); a1=fmaf(xv.x,wi1[i  ],a1); a2=fmaf(xv.x,wi2[i  ],a2);
      a0=fmaf(xv.y,wi0[i+1],a0); a1=fmaf(xv.y,wi1[i+1],a1); a2=fmaf(xv.y,wi2[i+1],a2);
      a0=fmaf(xv.z,wi0[i+2],a0); a1=fmaf(xv.z,wi1[i+2],a1); a2=fmaf(xv.z,wi2[i+2],a2);
      a0=fmaf(xv.w,wi0[i+3],a0); a1=fmaf(xv.w,wi1[i+3],a1); a2=fmaf(xv.w,wi2[i+3],a2);
      g0=fmaf(hv.x,wh0[i  ],g0); g1=fmaf(hv.x,wh1[i  ],g1); g2=fmaf(hv.x,wh2[i  ],g2);
      g0=fmaf(hv.y,wh0[i+1],g0); g1=fmaf(hv.y,wh1[i+1],g1); g2=fmaf(hv.y,wh2[i+1],g2);
      g0=fmaf(hv.z,wh0[i+2],g0); g1=fmaf(hv.z,wh1[i+2],g1); g2=fmaf(hv.z,wh2[i+2],g2);
      g0=fmaf(hv.w,wh0[i+3],g0); g1=fmaf(hv.w,wh1[i+3],g1); g2=fmaf(hv.w,wh2[i+3],g2);
    }
    pGI[hg*384+c]=a0; pGI[hg*384+128+c]=a1; pGI[hg*384+256+c]=a2;
    pGH[hg*384+c]=g0; pGH[hg*384+128+c]=g1; pGH[hg*384+256+c]=g2;
    __syncthreads();
    if (tid<128){
#pragma clang fp contract(off)
      float ir =((pGI[c]+pGI[384+c])+(pGI[768+c]+pGI[1152+c]))+bih_s[c];
      float iz =((pGI[128+c]+pGI[512+c])+(pGI[896+c]+pGI[1280+c]))+bih_s[128+c];
      float in_=((pGI[256+c]+pGI[640+c])+(pGI[1024+c]+pGI[1408+c]))+bih_s[256+c];
      float hr =((pGH[c]+pGH[384+c])+(pGH[768+c]+pGH[1152+c]))+bhh_s[c];
      float hz =((pGH[128+c]+pGH[512+c])+(pGH[896+c]+pGH[1280+c]))+bhh_s[128+c];
      float hn_=((pGH[256+c]+pGH[640+c])+(pGH[1024+c]+pGH[1408+c]))+bhh_s[256+c];
      float r = sigmoid_xla(ir+hr);
      float z = sigmoid_xla(iz+hz);
      float rh = r*hn_;
      float nn = tanh_xla(in_+rh);
      float hv = h_s[c];
      float hnew = (1.0f-z)*nn + z*hv;
      h_s[c]=hnew;
      EncOuts[(size_t)(b*256+t)*128+c]=hnew;
      if (t<255){
        float p0=pts[(size_t)(b*256+t+1)*2], p1=pts[(size_t)(b*256+t+1)*2+1];
        float v=fmaf(p1,fw1,p0*fw0)+fb;
        x_s[c]=fmaxf(v,0.f);
      }
    }
    __syncthreads();
  }
}

// --------------------------- Decoder, fully fused ---------------------------
// LDS float offsets:
#define OFF_W1E   0        // 32768  [h*256+n]
#define OFF_PG    32768    // 768
#define OFF_PI    33536    // 768
#define OFF_PQ    34304    // 256
#define OFF_PS    34560    // 256
#define OFF_H     34816    // 128
#define OFF_Q     34944    // 128
#define OFF_X     35072    // 128
#define OFF_VT    35200    // 128
#define OFF_BIH   35328    // 384
#define OFF_BHH   35712    // 384
#define OFF_SC    36096    // 256
#define OFF_RED   36352    // 16
#define OFF_ALIVE 36368    // 256 ints
#define OFF_ICTL  36624    // 16 ints
#define OFF_ENCS  36640    // 4096
#define DEC_LDS_FLOATS 40736

#define GI_PARTIAL() do{ \
  float a0=0,a1=0,a2=0; \
  const float4* xx4=(const float4*)&x_s[hg*64]; \
  _Pragma("unroll") \
  for (int i4=0;i4<16;++i4){ float4 xv=xx4[i4]; const int i=i4*4; \
    a0=fmaf(xv.x,wi0[i  ],a0); a1=fmaf(xv.x,wi1[i  ],a1); a2=fmaf(xv.x,wi2[i  ],a2); \
    a0=fmaf(xv.y,wi0[i+1],a0); a1=fmaf(xv.y,wi1[i+1],a1); a2=fmaf(xv.y,wi2[i+1],a2); \
    a0=fmaf(xv.z,wi0[i+2],a0); a1=fmaf(xv.z,wi1[i+2],a1); a2=fmaf(xv.z,wi2[i+2],a2); \
    a0=fmaf(xv.w,wi0[i+3],a0); a1=fmaf(xv.w,wi1[i+3],a1); a2=fmaf(xv.w,wi2[i+3],a2); } \
  pI[hg*384+c]=a0; pI[hg*384+128+c]=a1; pI[hg*384+256+c]=a2; }while(0)

__global__ __launch_bounds__(256,1) void dec_fused(
    const float* __restrict__ EncOuts, const float* __restrict__ pts,
    const float* __restrict__ wih, const float* __restrict__ whh,
    const float* __restrict__ bih, const float* __restrict__ bhh,
    const float* __restrict__ w1m, const float* __restrict__ w2m,
    const float* __restrict__ vtv, const float* __restrict__ spw,
    const float* __restrict__ spb, float* __restrict__ out)
{
  extern __shared__ float sm[];
  float* w1e  = sm + OFF_W1E;
  float* pG   = sm + OFF_PG;
  float* pI   = sm + OFF_PI;
  float* pQ   = sm + OFF_PQ;
  float* pS   = sm + OFF_PS;
  float* h_s  = sm + OFF_H;
  float* q_s  = sm + OFF_Q;
  float* x_s  = sm + OFF_X;
  float* vt_s = sm + OFF_VT;
  float* bih_s= sm + OFF_BIH;
  float* bhh_s= sm + OFF_BHH;
  float* sc_s = sm + OFF_SC;
  float* red  = sm + OFF_RED;
  int*   alive= (int*)(sm + OFF_ALIVE);
  int*   ictl = (int*)(sm + OFF_ICTL);
  float* encS = sm + OFF_ENCS;

  const int tid = threadIdx.x, b = blockIdx.x;
  const int hg = tid >> 7, c = tid & 127;

  if (tid<128){ vt_s[c]=vtv[c]; h_s[c]=EncOuts[(size_t)(b*256+255)*128+c]; }
  alive[tid]=tid;
  for (int e=tid;e<384;e+=256){ bih_s[e]=bih[e]; bhh_s[e]=bhh[e]; }
  if (tid==0){ ictl[0]=256; }

  // ---- w1e[h][n] = (EncOuts[b] @ w1)^T, computed in-kernel -----------------
  {
    float w1col[128];
    #pragma unroll
    for (int k=0;k<128;++k) w1col[k]=w1m[k*128+c];
    for (int ch=0; ch<8; ++ch){
      const float4* src=(const float4*)(EncOuts+(size_t)(b*256+ch*32)*128);
      for (int e=tid;e<1024;e+=256) ((float4*)encS)[e]=src[e];
      __syncthreads();
      for (int k2=0;k2<16;++k2){
        const int nn = hg + 2*k2;
        float acc=0.f;
        const float4* er=(const float4*)&encS[nn*128];
        #pragma unroll
        for (int k4=0;k4<32;++k4){
          float4 ev=er[k4]; const int k=k4*4;
          acc=fmaf(ev.x,w1col[k  ],acc);
          acc=fmaf(ev.y,w1col[k+1],acc);
          acc=fmaf(ev.z,w1col[k+2],acc);
          acc=fmaf(ev.w,w1col[k+3],acc);
        }
        w1e[c*256 + ch*32 + nn]=acc;
      }
      __syncthreads();
    }
  }

  // ---- register-resident decoder weights -----------------------------------
  float wi0[64],wi1[64],wi2[64],wh0[64],wh1[64],wh2[64],w2r[64];
  #pragma unroll
  for (int i=0;i<64;++i){
    int row=(hg*64+i)*384;
    wi0[i]=wih[row+c]; wi1[i]=wih[row+128+c]; wi2[i]=wih[row+256+c];
    wh0[i]=whh[row+c]; wh1[i]=whh[row+128+c]; wh2[i]=whh[row+256+c];
    w2r[i]=w2m[(hg*64+i)*128+c];
  }

  // ---- dec_input0 = mean(points[b]) @ sp_w + sp_b --------------------------
  {
    float s0=pts[(size_t)(b*256+tid)*2], s1=pts[(size_t)(b*256+tid)*2+1];
    #pragma unroll
    for (int off=32; off; off>>=1){ s0+=__shfl_down(s0,off); s1+=__shfl_down(s1,off); }
    if ((tid&63)==0){ red[tid>>6]=s0; red[4+(tid>>6)]=s1; }
  }
  __syncthreads();
  if (tid<128){
#pragma clang fp contract(off)
    float mp0=((red[0]+red[1])+(red[2]+red[3]))/256.0f;
    float mp1=((red[4]+red[5])+(red[6]+red[7]))/256.0f;
    float v=fmaf(mp1,spw[128+c],mp0*spw[c])+spb[c];
    x_s[c]=v;
  }
  __syncthreads();
  GI_PARTIAL();
  __syncthreads();

  float logp_acc=0.f;
  int cnt=256;
  for (int t=0;t<256;++t){
    // A: gh partials from h_s
    {
      float g0=0,g1=0,g2=0;
      const float4* hh4=(const float4*)&h_s[hg*64];
      #pragma unroll
      for (int i4=0;i4<16;++i4){
        float4 hv=hh4[i4]; const int i=i4*4;
        g0=fmaf(hv.x,wh0[i  ],g0); g1=fmaf(hv.x,wh1[i  ],g1); g2=fmaf(hv.x,wh2[i  ],g2);
        g0=fmaf(hv.y,wh0[i+1],g0); g1=fmaf(hv.y,wh1[i+1],g1); g2=fmaf(hv.y,wh2[i+1],g2);
        g0=fmaf(hv.z,wh0[i+2],g0); g1=fmaf(hv.z,wh1[i+2],g1); g2=fmaf(hv.z,wh2[i+2],g2);
        g0=fmaf(hv.w,wh0[i+3],g0); g1=fmaf(hv.w,wh1[i+3],g1); g2=fmaf(hv.w,wh2[i+3],g2);
      }
      pG[hg*384+c]=g0; pG[hg*384+128+c]=g1; pG[hg*384+256+c]=g2;
    }
    __syncthreads();                                   // S1
    // B: GRU pointwise
    if (tid<128){
#pragma clang fp contract(off)
      float ir =(pI[c]+pI[384+c])+bih_s[c];
      float iz =(pI[128+c]+pI[512+c])+bih_s[128+c];
      float in_=(pI[256+c]+pI[640+c])+bih_s[256+c];
      float hr =(pG[c]+pG[384+c])+bhh_s[c];
      float hz =(pG[128+c]+pG[512+c])+bhh_s[128+c];
      float hn_=(pG[256+c]+pG[640+c])+bhh_s[256+c];
      float r = sigmoid_xla(ir+hr);
      float z = sigmoid_xla(iz+hz);
      float rh = r*hn_;
      float nn = tanh_xla(in_+rh);
      float hv = h_s[c];
      h_s[c] = (1.0f-z)*nn + z*hv;
    }
    __syncthreads();                                   // S2
    // C: q partials from new h
    {
      float qp=0.f;
      const float4* hh4=(const float4*)&h_s[hg*64];
      #pragma unroll
      for (int i4=0;i4<16;++i4){
        float4 hv=hh4[i4]; const int i=i4*4;
        qp=fmaf(hv.x,w2r[i],qp); qp=fmaf(hv.y,w2r[i+1],qp);
        qp=fmaf(hv.z,w2r[i+2],qp); qp=fmaf(hv.w,w2r[i+3],qp);
      }
      pQ[hg*128+c]=qp;
    }
    __syncthreads();                                   // S3
    if (tid<128) q_s[c]=pQ[c]+pQ[128+c];
    __syncthreads();                                   // S4
    // E: scores, h-segmented across idle lanes
    int K=1;
    while ((cnt*(K<<1))<=256 && K<16) K<<=1;
    const int hlen=128/K;
    int seg, a2; bool act;
    if (K>1){ seg=(int)((unsigned)tid/(unsigned)cnt); a2=tid-seg*cnt; act=(seg<K); }
    else    { seg=0; a2=tid; act=(tid<cnt); }
    float part=0.f; int myn=0x7FFFFFFF;
    if (act){
      myn=alive[a2];
      const int h0=seg*hlen;
      for (int h=h0; h<h0+hlen; h+=4){
        float4 qv=*(const float4*)&q_s[h];
        float4 vv=*(const float4*)&vt_s[h];
        float w0=w1e[(h  )*256+myn];
        float w1v=w1e[(h+1)*256+myn];
        float w2v=w1e[(h+2)*256+myn];
        float w3=w1e[(h+3)*256+myn];
        part=fmaf(vv.x,tanh_xla(w0 +qv.x),part);
        part=fmaf(vv.y,tanh_xla(w1v+qv.y),part);
        part=fmaf(vv.z,tanh_xla(w2v+qv.z),part);
        part=fmaf(vv.w,tanh_xla(w3 +qv.w),part);
      }
    }
    float sc;
    if (K>1){
      if (act) pS[seg*cnt+a2]=part;
      __syncthreads();                                 // S4b
      sc=-INFINITY; myn=0x7FFFFFFF;
      if (tid<cnt){
        float s=pS[tid];
        for (int s2=1;s2<K;++s2) s+=pS[s2*cnt+tid];
        sc=s; myn=alive[tid];
      }
    } else {
      sc = act ? part : -INFINITY;
      if (!act) myn=0x7FFFFFFF;
    }
    float pert=-INFINITY;
    if (tid<cnt){
      sc_s[tid]=sc;
      uint32_t kk0,kk1,o0,o1;
      tf2x32(0u,42u,0u,(uint32_t)t,kk0,kk1);
      uint32_t f=(uint32_t)(b*256+myn);
      uint32_t bits;
#if RNG_PARTITIONABLE
      tf2x32(kk0,kk1,0u,f,o0,o1);
      bits=o0^o1;
#else
      { uint32_t p=(f<65536u)?f:(f-65536u);
        tf2x32(kk0,kk1,p,p+65536u,o0,o1);
        bits=(f<65536u)?o0:o1; }
#endif
      float fl=__uint_as_float((bits>>9)|0x3f800000u)-1.0f;
      float u=fmaxf(1.17549435e-38f, fl+1.17549435e-38f);
      float g=-logf(-logf(u));
      pert=g+sc;
    }
    // wave butterfly: argmax(pert) with low-n tie-break, max(sc)
    float bp=pert, bm=sc; int bn=myn, ba=tid;
    #pragma unroll
    for (int off=1; off<64; off<<=1){
      float op=__shfl_xor(bp,off); int on=__shfl_xor(bn,off); int oa=__shfl_xor(ba,off);
      float om=__shfl_xor(bm,off);
      if (op>bp || (op==bp && on<bn)){ bp=op; bn=on; ba=oa; }
      bm=fmaxf(bm,om);
    }
    float e_=(tid<cnt)?expf(sc-bm):0.f;
    #pragma unroll
    for (int off=1; off<64; off<<=1) e_+=__shfl_xor(e_,off);
    if ((tid&63)==0){
      int w=tid>>6;
      red[w]=bp; red[4+w]=bm; red[8+w]=e_;
      ictl[2+w]=bn; ictl[6+w]=ba;
    }
    __syncthreads();                                   // S5
    if (tid==0){
      float M=fmaxf(fmaxf(red[4],red[5]),fmaxf(red[6],red[7]));
      float S=0.f;
      #pragma unroll
      for (int w=0;w<4;++w){
        float ew=red[8+w];
        if (ew>0.f) S += ew*expf(red[4+w]-M);
      }
      float bp2=red[0]; int bn2=ictl[2], ba2=ictl[6];
      #pragma unroll
      for (int w=1;w<4;++w){
        float op=red[w]; int on=ictl[2+w];
        if (op>bp2 || (op==bp2 && on<bn2)){ bp2=op; bn2=on; ba2=ictl[6+w]; }
      }
      logp_acc += sc_s[ba2] - M - logf(S);
      out[b*256+t]=(float)bn2;
      ictl[1]=bn2;
      alive[ba2]=alive[cnt-1];
    }
    __syncthreads();                                   // S6
    cnt-=1;
    if (t<255){
      int bn=ictl[1];
      if (tid<128) x_s[c]=EncOuts[(size_t)(b*256+bn)*128+c];
      __syncthreads();                                 // S7
      GI_PARTIAL();
      // pI write -> next iter's B read is ordered by S1.
    }
  }
  if (tid==0) out[131072+b]=logp_acc;
}

// --------------------------- telemetry fallback -----------------------------
__global__ void k_telemetry(float* __restrict__ out, int n, float val){
  int i=blockIdx.x*blockDim.x+threadIdx.x;
  if (i<n) out[i]=val;
}

// ---------------------------------------------------------------------------
extern "C" void kernel_launch(void* const* d_in, const int* in_sizes, int n_in,
                              void* d_out, int out_size, void* d_ws, size_t ws_size,
                              hipStream_t stream){
  const float* points  = (const float*)d_in[0];
  const float* fc_w    = (const float*)d_in[1];
  const float* fc_b    = (const float*)d_in[2];
  const float* enc_wih = (const float*)d_in[3];
  const float* enc_whh = (const float*)d_in[4];
  const float* enc_bih = (const float*)d_in[5];
  const float* enc_bhh = (const float*)d_in[6];
  const float* dec_wih = (const float*)d_in[7];
  const float* dec_whh = (const float*)d_in[8];
  const float* dec_bih = (const float*)d_in[9];
  const float* dec_bhh = (const float*)d_in[10];
  const float* w1      = (const float*)d_in[11];
  const float* w2      = (const float*)d_in[12];
  const float* vt      = (const float*)d_in[13];
  const float* sp_w    = (const float*)d_in[14];
  const float* sp_b    = (const float*)d_in[15];
  float* out = (float*)d_out;

  const size_t need = (size_t)131072*128*4;   // EncOuts, 64 MiB
  if (ws_size < need){
    k_telemetry<<<(out_size+255)/256,256,0,stream>>>(out, out_size, (float)(ws_size>>20));
    return;
  }
  float* EncOuts = (float*)d_ws;

  enc_fused<<<512,512,0,stream>>>(points, fc_w, fc_b, enc_wih, enc_whh,
                                  enc_bih, enc_bhh, EncOuts);

  const int dec_lds = DEC_LDS_FLOATS*4;       // 162,944 B <= 160 KiB pool
  (void)hipFuncSetAttribute((const void*)dec_fused,
                            hipFuncAttributeMaxDynamicSharedMemorySize, dec_lds);
  dec_fused<<<512,256,dec_lds,stream>>>(EncOuts, points, dec_wih, dec_whh,
      dec_bih, dec_bhh, w1, w2, vt, sp_w, sp_b, out);
}

// Round 3
// 6440.214 us; speedup vs baseline: 1.0756x; 1.0756x over previous
//
#include <hip/hip_runtime.h>
#include <math.h>
#include <stdint.h>

// ---------------------------------------------------------------------------
// PointerNet, MI355X. R3: 512-thread decoder (2 waves/SIMD), DecGI precompute
// (ws >= 256MiB fast path), stride-257 w1e, shuffle-reduced segmented scores.
// Fallback = round-2 kernel verbatim (proven, absmax 0).
// ---------------------------------------------------------------------------

#define RNG_PARTITIONABLE 1

__device__ __forceinline__ uint32_t rotl32_(uint32_t v, int r){ return (v<<r)|(v>>(32-r)); }

__device__ __forceinline__ void tf2x32(uint32_t k0, uint32_t k1, uint32_t x0, uint32_t x1,
                                       uint32_t& o0, uint32_t& o1){
  uint32_t k2 = k0 ^ k1 ^ 0x1BD11BDAu;
  x0 += k0; x1 += k1;
  x0 += x1; x1 = rotl32_(x1,13); x1 ^= x0;
  x0 += x1; x1 = rotl32_(x1,15); x1 ^= x0;
  x0 += x1; x1 = rotl32_(x1,26); x1 ^= x0;
  x0 += x1; x1 = rotl32_(x1, 6); x1 ^= x0;
  x0 += k1; x1 += k2 + 1u;
  x0 += x1; x1 = rotl32_(x1,17); x1 ^= x0;
  x0 += x1; x1 = rotl32_(x1,29); x1 ^= x0;
  x0 += x1; x1 = rotl32_(x1,16); x1 ^= x0;
  x0 += x1; x1 = rotl32_(x1,24); x1 ^= x0;
  x0 += k2; x1 += k0 + 2u;
  x0 += x1; x1 = rotl32_(x1,13); x1 ^= x0;
  x0 += x1; x1 = rotl32_(x1,15); x1 ^= x0;
  x0 += x1; x1 = rotl32_(x1,26); x1 ^= x0;
  x0 += x1; x1 = rotl32_(x1, 6); x1 ^= x0;
  x0 += k0; x1 += k1 + 3u;
  x0 += x1; x1 = rotl32_(x1,17); x1 ^= x0;
  x0 += x1; x1 = rotl32_(x1,29); x1 ^= x0;
  x0 += x1; x1 = rotl32_(x1,16); x1 ^= x0;
  x0 += x1; x1 = rotl32_(x1,24); x1 ^= x0;
  x0 += k1; x1 += k2 + 4u;
  x0 += x1; x1 = rotl32_(x1,13); x1 ^= x0;
  x0 += x1; x1 = rotl32_(x1,15); x1 ^= x0;
  x0 += x1; x1 = rotl32_(x1,26); x1 ^= x0;
  x0 += x1; x1 = rotl32_(x1, 6); x1 ^= x0;
  x0 += k2; x1 += k0 + 5u;
  o0 = x0; o1 = x1;
}

__device__ __forceinline__ float tanh_xla(float x){
#pragma clang fp contract(off)
  float xc = fminf(fmaxf(x, -9.0f), 9.0f);
  float x2 = xc*xc;
  float num = -2.76076847742355e-16f;
  num = x2*num + 2.00018790482477e-13f;
  num = x2*num + (-8.60467152213735e-11f);
  num = x2*num + 5.12229709037114e-08f;
  num = x2*num + 1.48572235717979e-05f;
  num = x2*num + 6.37261928875436e-04f;
  num = x2*num + 4.89352455891786e-03f;
  num = xc*num;
  float den = 1.19825839466702e-06f;
  den = x2*den + 1.18534705686654e-04f;
  den = x2*den + 2.26843463243900e-03f;
  den = x2*den + 4.89352518554385e-03f;
  float r = num/den;
  return (fabsf(x) < 4e-4f) ? x : r;
}

__device__ __forceinline__ float sigmoid_xla(float x){
  return 1.0f/(1.0f + expf(-x));
}

// --------------------------- Encoder (unchanged, proven) --------------------
__global__ __launch_bounds__(512,2) void enc_fused(
    const float* __restrict__ pts, const float* __restrict__ fcw, const float* __restrict__ fcb,
    const float* __restrict__ wih, const float* __restrict__ whh,
    const float* __restrict__ bih, const float* __restrict__ bhh,
    float* __restrict__ EncOuts)
{
  __shared__ float x_s[128], h_s[128], pGI[1536], pGH[1536], bih_s[384], bhh_s[384];
  const int tid = threadIdx.x, b = blockIdx.x;
  const int hg = tid >> 7, c = tid & 127;
  float wi0[32],wi1[32],wi2[32],wh0[32],wh1[32],wh2[32];
  #pragma unroll
  for (int i=0;i<32;++i){
    int row = (hg*32+i)*384;
    wi0[i]=wih[row+c]; wi1[i]=wih[row+128+c]; wi2[i]=wih[row+256+c];
    wh0[i]=whh[row+c]; wh1[i]=whh[row+128+c]; wh2[i]=whh[row+256+c];
  }
  if (tid<384){ bih_s[tid]=bih[tid]; bhh_s[tid]=bhh[tid]; }
  float fw0=0.f,fw1=0.f,fb=0.f;
  if (tid<128){
#pragma clang fp contract(off)
    fw0=fcw[c]; fw1=fcw[128+c]; fb=fcb[c];
    h_s[c]=0.f;
    float p0=pts[(size_t)b*512], p1=pts[(size_t)b*512+1];
    float v = fmaf(p1,fw1,p0*fw0)+fb;
    x_s[c]=fmaxf(v,0.f);
  }
  __syncthreads();
  for (int t=0;t<256;++t){
    float a0=0,a1=0,a2=0,g0=0,g1=0,g2=0;
    const float4* x4=(const float4*)&x_s[hg*32];
    const float4* h4=(const float4*)&h_s[hg*32];
    #pragma unroll
    for (int i4=0;i4<8;++i4){
      float4 xv=x4[i4], hv=h4[i4];
      const int i=i4*4;
      a0=fmaf(xv.x,wi0[i  ],a0); a1=fmaf(xv.x,wi1[i  ],a1); a2=fmaf(xv.x,wi2[i  ],a2);
      a0=fmaf(xv.y,wi0[i+1],a0); a1=fmaf(xv.y,wi1[i+1],a1); a2=fmaf(xv.y,wi2[i+1],a2);
      a0=fmaf(xv.z,wi0[i+2],a0); a1=fmaf(xv.z,wi1[i+2],a1); a2=fmaf(xv.z,wi2[i+2],a2);
      a0=fmaf(xv.w,wi0[i+3],a0); a1=fmaf(xv.w,wi1[i+3],a1); a2=fmaf(xv.w,wi2[i+3],a2);
      g0=fmaf(hv.x,wh0[i  ],g0); g1=fmaf(hv.x,wh1[i  ],g1); g2=fmaf(hv.x,wh2[i  ],g2);
      g0=fmaf(hv.y,wh0[i+1],g0); g1=fmaf(hv.y,wh1[i+1],g1); g2=fmaf(hv.y,wh2[i+1],g2);
      g0=fmaf(hv.z,wh0[i+2],g0); g1=fmaf(hv.z,wh1[i+2],g1); g2=fmaf(hv.z,wh2[i+2],g2);
      g0=fmaf(hv.w,wh0[i+3],g0); g1=fmaf(hv.w,wh1[i+3],g1); g2=fmaf(hv.w,wh2[i+3],g2);
    }
    pGI[hg*384+c]=a0; pGI[hg*384+128+c]=a1; pGI[hg*384+256+c]=a2;
    pGH[hg*384+c]=g0; pGH[hg*384+128+c]=g1; pGH[hg*384+256+c]=g2;
    __syncthreads();
    if (tid<128){
#pragma clang fp contract(off)
      float ir =((pGI[c]+pGI[384+c])+(pGI[768+c]+pGI[1152+c]))+bih_s[c];
      float iz =((pGI[128+c]+pGI[512+c])+(pGI[896+c]+pGI[1280+c]))+bih_s[128+c];
      float in_=((pGI[256+c]+pGI[640+c])+(pGI[1024+c]+pGI[1408+c]))+bih_s[256+c];
      float hr =((pGH[c]+pGH[384+c])+(pGH[768+c]+pGH[1152+c]))+bhh_s[c];
      float hz =((pGH[128+c]+pGH[512+c])+(pGH[896+c]+pGH[1280+c]))+bhh_s[128+c];
      float hn_=((pGH[256+c]+pGH[640+c])+(pGH[1024+c]+pGH[1408+c]))+bhh_s[256+c];
      float r = sigmoid_xla(ir+hr);
      float z = sigmoid_xla(iz+hz);
      float rh = r*hn_;
      float nn = tanh_xla(in_+rh);
      float hv = h_s[c];
      float hnew = (1.0f-z)*nn + z*hv;
      h_s[c]=hnew;
      EncOuts[(size_t)(b*256+t)*128+c]=hnew;
      if (t<255){
        float p0=pts[(size_t)(b*256+t+1)*2], p1=pts[(size_t)(b*256+t+1)*2+1];
        float v=fmaf(p1,fw1,p0*fw0)+fb;
        x_s[c]=fmaxf(v,0.f);
      }
    }
    __syncthreads();
  }
}

// --------------------------- DecGI = EncOuts @ dec_wih + bih ----------------
__global__ __launch_bounds__(384) void gemm_decgi(
    const float* __restrict__ EncOuts, const float* __restrict__ wih,
    const float* __restrict__ bih, float* __restrict__ DecGI)
{
  __shared__ float As[64*128];
  const int tid = threadIdx.x;
  const int row0 = blockIdx.x*64;
  const float4* src = (const float4*)(EncOuts + (size_t)row0*128);
  for (int e=tid; e<2048; e+=384) ((float4*)As)[e]=src[e];
  float bvk[128];
  #pragma unroll
  for (int k=0;k<128;++k) bvk[k]=wih[k*384+tid];
  float bb = bih[tid];
  __syncthreads();
  for (int r=0;r<64;++r){
    float a=0.f;
    const float4* Ar=(const float4*)&As[r*128];
    #pragma unroll
    for (int k4=0;k4<32;++k4){
      float4 av=Ar[k4]; const int k=k4*4;
      a=fmaf(av.x,bvk[k  ],a);
      a=fmaf(av.y,bvk[k+1],a);
      a=fmaf(av.z,bvk[k+2],a);
      a=fmaf(av.w,bvk[k+3],a);
    }
    DecGI[(size_t)(row0+r)*384 + tid] = a + bb;
  }
}

// --------------------------- Decoder v2: 512 thr, DecGI path ----------------
// LDS float offsets (total 36664 floats = 146,656 B):
#define D2_W1E   0        // 128*257 = 32896, stride 257
#define D2_PG    32896    // 1536
#define D2_PQ    34432    // 512
#define D2_GI    34944    // 384
#define D2_H     35328    // 128
#define D2_Q     35456    // 128
#define D2_VT    35584    // 128
#define D2_BHH   35712    // 384
#define D2_SC    36096    // 256
#define D2_RED   36352    // 32
#define D2_ALIVE 36384    // 256 ints
#define D2_ICTL  36640    // 24 ints
#define D2_ENCS  32896    // alias over PG+PQ (2048 floats), init only
#define D2_LDS_FLOATS 36664

__global__ __launch_bounds__(512,2) void dec_fused2(
    const float* __restrict__ EncOuts, const float* __restrict__ DecGI,
    const float* __restrict__ pts,
    const float* __restrict__ wih, const float* __restrict__ whh,
    const float* __restrict__ bih, const float* __restrict__ bhh,
    const float* __restrict__ w1m, const float* __restrict__ w2m,
    const float* __restrict__ vtv, const float* __restrict__ spw,
    const float* __restrict__ spb, float* __restrict__ out)
{
  extern __shared__ float sm[];
  float* w1e  = sm + D2_W1E;
  float* pG   = sm + D2_PG;
  float* pQ   = sm + D2_PQ;
  float* gi_s = sm + D2_GI;
  float* h_s  = sm + D2_H;
  float* q_s  = sm + D2_Q;
  float* vt_s = sm + D2_VT;
  float* bhh_s= sm + D2_BHH;
  float* sc_s = sm + D2_SC;
  float* red  = sm + D2_RED;
  int*   alive= (int*)(sm + D2_ALIVE);
  int*   ictl = (int*)(sm + D2_ICTL);
  float* encS = sm + D2_ENCS;

  const int tid = threadIdx.x, b = blockIdx.x;
  const int hg = tid >> 7, c = tid & 127;

  if (tid<128){ vt_s[c]=vtv[c]; h_s[c]=EncOuts[(size_t)(b*256+255)*128+c]; }
  if (tid<256) alive[tid]=tid;
  for (int e=tid;e<384;e+=512) bhh_s[e]=bhh[e];

  // ---- w1e[h*257+n] = (EncOuts[b] @ w1)^T -----------------------------------
  {
    float w1col[128];
    #pragma unroll
    for (int k=0;k<128;++k) w1col[k]=w1m[k*128+c];
    for (int ch=0; ch<16; ++ch){
      __syncthreads();
      ((float4*)encS)[tid] = ((const float4*)(EncOuts + (size_t)(b*256+ch*16)*128))[tid];
      __syncthreads();
      #pragma unroll
      for (int j=0;j<4;++j){
        const int nl = hg*4 + j;
        float acc=0.f;
        const float4* er=(const float4*)&encS[nl*128];
        #pragma unroll
        for (int k4=0;k4<32;++k4){
          float4 ev=er[k4]; const int k=k4*4;
          acc=fmaf(ev.x,w1col[k  ],acc);
          acc=fmaf(ev.y,w1col[k+1],acc);
          acc=fmaf(ev.z,w1col[k+2],acc);
          acc=fmaf(ev.w,w1col[k+3],acc);
        }
        w1e[c*257 + ch*16 + nl]=acc;
      }
    }
  }
  __syncthreads();

  // ---- decoder weights: 32 rows x (3 whh + w2) per thread -------------------
  float wh0[32],wh1[32],wh2[32],w2r[32];
  #pragma unroll
  for (int i=0;i<32;++i){
    int row=(hg*32+i)*384;
    wh0[i]=whh[row+c]; wh1[i]=whh[row+128+c]; wh2[i]=whh[row+256+c];
    w2r[i]=w2m[(hg*32+i)*128+c];
  }

  // ---- dec_input0 = mean(points[b]) @ sp_w + sp_b  -> q_s (temp) ------------
  if (tid<256){
    float s0=pts[(size_t)(b*256+tid)*2], s1=pts[(size_t)(b*256+tid)*2+1];
    #pragma unroll
    for (int off=32; off; off>>=1){ s0+=__shfl_down(s0,off); s1+=__shfl_down(s1,off); }
    if ((tid&63)==0){ red[tid>>6]=s0; red[4+(tid>>6)]=s1; }
  }
  __syncthreads();
  if (tid<128){
#pragma clang fp contract(off)
    float mp0=((red[0]+red[1])+(red[2]+red[3]))/256.0f;
    float mp1=((red[4]+red[5])+(red[6]+red[7]))/256.0f;
    q_s[c]=fmaf(mp1,spw[128+c],mp0*spw[c])+spb[c];
  }
  __syncthreads();
  // gi0 = x0 @ wih + bih  (one-time, wih from global)
  if (tid<384){
    float acc=0.f;
    for (int k=0;k<128;++k) acc=fmaf(q_s[k], wih[k*384+tid], acc);
    gi_s[tid]=acc+bih[tid];
  }
  __syncthreads();

  float logp_acc=0.f;
  int cnt=256;
  for (int t=0;t<256;++t){
    // A: gh partials
    {
      float g0=0,g1=0,g2=0;
      const float4* h4=(const float4*)&h_s[hg*32];
      #pragma unroll
      for (int i4=0;i4<8;++i4){
        float4 hv=h4[i4]; const int i=i4*4;
        g0=fmaf(hv.x,wh0[i  ],g0); g1=fmaf(hv.x,wh1[i  ],g1); g2=fmaf(hv.x,wh2[i  ],g2);
        g0=fmaf(hv.y,wh0[i+1],g0); g1=fmaf(hv.y,wh1[i+1],g1); g2=fmaf(hv.y,wh2[i+1],g2);
        g0=fmaf(hv.z,wh0[i+2],g0); g1=fmaf(hv.z,wh1[i+2],g1); g2=fmaf(hv.z,wh2[i+2],g2);
        g0=fmaf(hv.w,wh0[i+3],g0); g1=fmaf(hv.w,wh1[i+3],g1); g2=fmaf(hv.w,wh2[i+3],g2);
      }
      pG[hg*384+c]=g0; pG[hg*384+128+c]=g1; pG[hg*384+256+c]=g2;
    }
    __syncthreads();                                   // S1
    // B: GRU pointwise (gi_s already includes bih)
    if (tid<128){
#pragma clang fp contract(off)
      float hr =((pG[c]+pG[384+c])+(pG[768+c]+pG[1152+c]))+bhh_s[c];
      float hz =((pG[128+c]+pG[512+c])+(pG[896+c]+pG[1280+c]))+bhh_s[128+c];
      float hn_=((pG[256+c]+pG[640+c])+(pG[1024+c]+pG[1408+c]))+bhh_s[256+c];
      float r = sigmoid_xla(gi_s[c]+hr);
      float z = sigmoid_xla(gi_s[128+c]+hz);
      float rh = r*hn_;
      float nn = tanh_xla(gi_s[256+c]+rh);
      float hv = h_s[c];
      h_s[c] = (1.0f-z)*nn + z*hv;
    }
    __syncthreads();                                   // S2
    // C: q partials
    {
      float qp=0.f;
      const float4* h4=(const float4*)&h_s[hg*32];
      #pragma unroll
      for (int i4=0;i4<8;++i4){
        float4 hv=h4[i4]; const int i=i4*4;
        qp=fmaf(hv.x,w2r[i],qp); qp=fmaf(hv.y,w2r[i+1],qp);
        qp=fmaf(hv.z,w2r[i+2],qp); qp=fmaf(hv.w,w2r[i+3],qp);
      }
      pQ[hg*128+c]=qp;
    }
    __syncthreads();                                   // S3
    if (tid<128) q_s[c]=((pQ[c]+pQ[128+c])+(pQ[256+c]+pQ[384+c]));
    __syncthreads();                                   // S4
    // E: segmented scores, candidate segs in consecutive lanes
    int K, ksh;
    if      (cnt>128){K=2; ksh=1;}
    else if (cnt> 64){K=4; ksh=2;}
    else if (cnt> 32){K=8; ksh=3;}
    else if (cnt> 16){K=16;ksh=4;}
    else             {K=32;ksh=5;}
    const int hlen = 128>>ksh;
    const int a2 = tid>>ksh, seg = tid&(K-1);
    const bool act = a2 < cnt;
    float part=0.f; int myn=0x7FFFFFFF;
    if (act){
      myn=alive[a2];
      const int h0=seg*hlen;
      for (int h=h0; h<h0+hlen; h+=4){
        float4 qv=*(const float4*)&q_s[h];
        float4 vv=*(const float4*)&vt_s[h];
        float w0 =w1e[(h  )*257+myn];
        float w1v=w1e[(h+1)*257+myn];
        float w2v=w1e[(h+2)*257+myn];
        float w3 =w1e[(h+3)*257+myn];
        part=fmaf(vv.x,tanh_xla(w0 +qv.x),part);
        part=fmaf(vv.y,tanh_xla(w1v+qv.y),part);
        part=fmaf(vv.z,tanh_xla(w2v+qv.z),part);
        part=fmaf(vv.w,tanh_xla(w3 +qv.w),part);
      }
    }
    for (int off=1; off<K; off<<=1) part += __shfl_xor(part, off);
    float sc = act ? part : -INFINITY;
    float pert=-INFINITY;
    if (act && seg==0){
      sc_s[a2]=sc;
      uint32_t kk0,kk1,o0,o1;
      tf2x32(0u,42u,0u,(uint32_t)t,kk0,kk1);
      uint32_t f=(uint32_t)(b*256+myn);
      uint32_t bits;
#if RNG_PARTITIONABLE
      tf2x32(kk0,kk1,0u,f,o0,o1);
      bits=o0^o1;
#else
      { uint32_t p=(f<65536u)?f:(f-65536u);
        tf2x32(kk0,kk1,p,p+65536u,o0,o1);
        bits=(f<65536u)?o0:o1; }
#endif
      float fl=__uint_as_float((bits>>9)|0x3f800000u)-1.0f;
      float u=fmaxf(1.17549435e-38f, fl+1.17549435e-38f);
      float g=-logf(-logf(u));
      pert=g+sc;
    } else {
      sc=-INFINITY; myn=0x7FFFFFFF;      // only seg0 lanes carry stats
    }
    float bp=pert, bm=sc; int bn=myn, ba=a2;
    #pragma unroll
    for (int off=1; off<64; off<<=1){
      float op=__shfl_xor(bp,off); int on=__shfl_xor(bn,off); int oa=__shfl_xor(ba,off);
      float om=__shfl_xor(bm,off);
      if (op>bp || (op==bp && on<bn)){ bp=op; bn=on; ba=oa; }
      bm=fmaxf(bm,om);
    }
    float e_=(pert>-INFINITY)?expf(sc-bm):0.f;
    #pragma unroll
    for (int off=1; off<64; off<<=1) e_+=__shfl_xor(e_,off);
    if ((tid&63)==0){
      int w=tid>>6;
      red[w]=bp; red[8+w]=bm; red[16+w]=e_;
      ictl[2+w]=bn; ictl[10+w]=ba;
    }
    __syncthreads();                                   // S5
    if (tid==0){
      float M=red[8];
      #pragma unroll
      for (int w=1;w<8;++w) M=fmaxf(M,red[8+w]);
      float S=0.f;
      #pragma unroll
      for (int w=0;w<8;++w){
        float ew=red[16+w];
        if (ew>0.f) S += ew*expf(red[8+w]-M);
      }
      float bp2=red[0]; int bn2=ictl[2], ba2=ictl[10];
      #pragma unroll
      for (int w=1;w<8;++w){
        float op=red[w]; int on=ictl[2+w];
        if (op>bp2 || (op==bp2 && on<bn2)){ bp2=op; bn2=on; ba2=ictl[10+w]; }
      }
      logp_acc += sc_s[ba2] - M - logf(S);
      out[b*256+t]=(float)bn2;
      ictl[1]=bn2;
      alive[ba2]=alive[cnt-1];
    }
    __syncthreads();                                   // S6
    cnt-=1;
    if (t<255){
      int bn=ictl[1];
      if (tid<384) gi_s[tid]=DecGI[(size_t)(b*256+bn)*384+tid];
      // ordered before B's read by next iteration's S1
    }
  }
  if (tid==0) out[131072+b]=logp_acc;
}

// --------------------------- Fallback decoder (round-2, proven) -------------
#define OFF_W1E   0
#define OFF_PG    32768
#define OFF_PI    33536
#define OFF_PQ    34304
#define OFF_PS    34560
#define OFF_H     34816
#define OFF_Q     34944
#define OFF_X     35072
#define OFF_VT    35200
#define OFF_BIH   35328
#define OFF_BHH   35712
#define OFF_SC    36096
#define OFF_RED   36352
#define OFF_ALIVE 36368
#define OFF_ICTL  36624
#define OFF_ENCS  36640
#define DEC_LDS_FLOATS 40736

#define GI_PARTIAL() do{ \
  float a0=0,a1=0,a2=0; \
  const float4* xx4=(const float4*)&x_s[hg*64]; \
  _Pragma("unroll") \
  for (int i4=0;i4<16;++i4){ float4 xv=xx4[i4]; const int i=i4*4; \
    a0=fmaf(xv.x,wi0[i  ],a0); a1=fmaf(xv.x,wi1[i  ],a1); a2=fmaf(xv.x,wi2[i  ],a2); \
    a0=fmaf(xv.y,wi0[i+1],a0); a1=fmaf(xv.y,wi1[i+1],a1); a2=fmaf(xv.y,wi2[i+1],a2); \
    a0=fmaf(xv.z,wi0[i+2],a0); a1=fmaf(xv.z,wi1[i+2],a1); a2=fmaf(xv.z,wi2[i+2],a2); \
    a0=fmaf(xv.w,wi0[i+3],a0); a1=fmaf(xv.w,wi1[i+3],a1); a2=fmaf(xv.w,wi2[i+3],a2); } \
  pI[hg*384+c]=a0; pI[hg*384+128+c]=a1; pI[hg*384+256+c]=a2; }while(0)

__global__ __launch_bounds__(256,1) void dec_fused_fb(
    const float* __restrict__ EncOuts, const float* __restrict__ pts,
    const float* __restrict__ wih, const float* __restrict__ whh,
    const float* __restrict__ bih, const float* __restrict__ bhh,
    const float* __restrict__ w1m, const float* __restrict__ w2m,
    const float* __restrict__ vtv, const float* __restrict__ spw,
    const float* __restrict__ spb, float* __restrict__ out)
{
  extern __shared__ float sm[];
  float* w1e  = sm + OFF_W1E;
  float* pG   = sm + OFF_PG;
  float* pI   = sm + OFF_PI;
  float* pQ   = sm + OFF_PQ;
  float* pS   = sm + OFF_PS;
  float* h_s  = sm + OFF_H;
  float* q_s  = sm + OFF_Q;
  float* x_s  = sm + OFF_X;
  float* vt_s = sm + OFF_VT;
  float* bih_s= sm + OFF_BIH;
  float* bhh_s= sm + OFF_BHH;
  float* sc_s = sm + OFF_SC;
  float* red  = sm + OFF_RED;
  int*   alive= (int*)(sm + OFF_ALIVE);
  int*   ictl = (int*)(sm + OFF_ICTL);
  float* encS = sm + OFF_ENCS;

  const int tid = threadIdx.x, b = blockIdx.x;
  const int hg = tid >> 7, c = tid & 127;

  if (tid<128){ vt_s[c]=vtv[c]; h_s[c]=EncOuts[(size_t)(b*256+255)*128+c]; }
  alive[tid]=tid;
  for (int e=tid;e<384;e+=256){ bih_s[e]=bih[e]; bhh_s[e]=bhh[e]; }
  if (tid==0){ ictl[0]=256; }

  {
    float w1col[128];
    #pragma unroll
    for (int k=0;k<128;++k) w1col[k]=w1m[k*128+c];
    for (int ch=0; ch<8; ++ch){
      const float4* src=(const float4*)(EncOuts+(size_t)(b*256+ch*32)*128);
      for (int e=tid;e<1024;e+=256) ((float4*)encS)[e]=src[e];
      __syncthreads();
      for (int k2=0;k2<16;++k2){
        const int nn = hg + 2*k2;
        float acc=0.f;
        const float4* er=(const float4*)&encS[nn*128];
        #pragma unroll
        for (int k4=0;k4<32;++k4){
          float4 ev=er[k4]; const int k=k4*4;
          acc=fmaf(ev.x,w1col[k  ],acc);
          acc=fmaf(ev.y,w1col[k+1],acc);
          acc=fmaf(ev.z,w1col[k+2],acc);
          acc=fmaf(ev.w,w1col[k+3],acc);
        }
        w1e[c*256 + ch*32 + nn]=acc;
      }
      __syncthreads();
    }
  }

  float wi0[64],wi1[64],wi2[64],wh0[64],wh1[64],wh2[64],w2r[64];
  #pragma unroll
  for (int i=0;i<64;++i){
    int row=(hg*64+i)*384;
    wi0[i]=wih[row+c]; wi1[i]=wih[row+128+c]; wi2[i]=wih[row+256+c];
    wh0[i]=whh[row+c]; wh1[i]=whh[row+128+c]; wh2[i]=whh[row+256+c];
    w2r[i]=w2m[(hg*64+i)*128+c];
  }

  {
    float s0=pts[(size_t)(b*256+tid)*2], s1=pts[(size_t)(b*256+tid)*2+1];
    #pragma unroll
    for (int off=32; off; off>>=1){ s0+=__shfl_down(s0,off); s1+=__shfl_down(s1,off); }
    if ((tid&63)==0){ red[tid>>6]=s0; red[4+(tid>>6)]=s1; }
  }
  __syncthreads();
  if (tid<128){
#pragma clang fp contract(off)
    float mp0=((red[0]+red[1])+(red[2]+red[3]))/256.0f;
    float mp1=((red[4]+red[5])+(red[6]+red[7]))/256.0f;
    float v=fmaf(mp1,spw[128+c],mp0*spw[c])+spb[c];
    x_s[c]=v;
  }
  __syncthreads();
  GI_PARTIAL();
  __syncthreads();

  float logp_acc=0.f;
  int cnt=256;
  for (int t=0;t<256;++t){
    {
      float g0=0,g1=0,g2=0;
      const float4* hh4=(const float4*)&h_s[hg*64];
      #pragma unroll
      for (int i4=0;i4<16;++i4){
        float4 hv=hh4[i4]; const int i=i4*4;
        g0=fmaf(hv.x,wh0[i  ],g0); g1=fmaf(hv.x,wh1[i  ],g1); g2=fmaf(hv.x,wh2[i  ],g2);
        g0=fmaf(hv.y,wh0[i+1],g0); g1=fmaf(hv.y,wh1[i+1],g1); g2=fmaf(hv.y,wh2[i+1],g2);
        g0=fmaf(hv.z,wh0[i+2],g0); g1=fmaf(hv.z,wh1[i+2],g1); g2=fmaf(hv.z,wh2[i+2],g2);
        g0=fmaf(hv.w,wh0[i+3],g0); g1=fmaf(hv.w,wh1[i+3],g1); g2=fmaf(hv.w,wh2[i+3],g2);
      }
      pG[hg*384+c]=g0; pG[hg*384+128+c]=g1; pG[hg*384+256+c]=g2;
    }
    __syncthreads();
    if (tid<128){
#pragma clang fp contract(off)
      float ir =(pI[c]+pI[384+c])+bih_s[c];
      float iz =(pI[128+c]+pI[512+c])+bih_s[128+c];
      float in_=(pI[256+c]+pI[640+c])+bih_s[256+c];
      float hr =(pG[c]+pG[384+c])+bhh_s[c];
      float hz =(pG[128+c]+pG[512+c])+bhh_s[128+c];
      float hn_=(pG[256+c]+pG[640+c])+bhh_s[256+c];
      float r = sigmoid_xla(ir+hr);
      float z = sigmoid_xla(iz+hz);
      float rh = r*hn_;
      float nn = tanh_xla(in_+rh);
      float hv = h_s[c];
      h_s[c] = (1.0f-z)*nn + z*hv;
    }
    __syncthreads();
    {
      float qp=0.f;
      const float4* hh4=(const float4*)&h_s[hg*64];
      #pragma unroll
      for (int i4=0;i4<16;++i4){
        float4 hv=hh4[i4]; const int i=i4*4;
        qp=fmaf(hv.x,w2r[i],qp); qp=fmaf(hv.y,w2r[i+1],qp);
        qp=fmaf(hv.z,w2r[i+2],qp); qp=fmaf(hv.w,w2r[i+3],qp);
      }
      pQ[hg*128+c]=qp;
    }
    __syncthreads();
    if (tid<128) q_s[c]=pQ[c]+pQ[128+c];
    __syncthreads();
    int K=1;
    while ((cnt*(K<<1))<=256 && K<16) K<<=1;
    const int hlen=128/K;
    int seg, a2; bool act;
    if (K>1){ seg=(int)((unsigned)tid/(unsigned)cnt); a2=tid-seg*cnt; act=(seg<K); }
    else    { seg=0; a2=tid; act=(tid<cnt); }
    float part=0.f; int myn=0x7FFFFFFF;
    if (act){
      myn=alive[a2];
      const int h0=seg*hlen;
      for (int h=h0; h<h0+hlen; h+=4){
        float4 qv=*(const float4*)&q_s[h];
        float4 vv=*(const float4*)&vt_s[h];
        float w0=w1e[(h  )*256+myn];
        float w1v=w1e[(h+1)*256+myn];
        float w2v=w1e[(h+2)*256+myn];
        float w3=w1e[(h+3)*256+myn];
        part=fmaf(vv.x,tanh_xla(w0 +qv.x),part);
        part=fmaf(vv.y,tanh_xla(w1v+qv.y),part);
        part=fmaf(vv.z,tanh_xla(w2v+qv.z),part);
        part=fmaf(vv.w,tanh_xla(w3 +qv.w),part);
      }
    }
    float sc;
    if (K>1){
      if (act) pS[seg*cnt+a2]=part;
      __syncthreads();
      sc=-INFINITY; myn=0x7FFFFFFF;
      if (tid<cnt){
        float s=pS[tid];
        for (int s2=1;s2<K;++s2) s+=pS[s2*cnt+tid];
        sc=s; myn=alive[tid];
      }
    } else {
      sc = act ? part : -INFINITY;
      if (!act) myn=0x7FFFFFFF;
    }
    float pert=-INFINITY;
    if (tid<cnt){
      sc_s[tid]=sc;
      uint32_t kk0,kk1,o0,o1;
      tf2x32(0u,42u,0u,(uint32_t)t,kk0,kk1);
      uint32_t f=(uint32_t)(b*256+myn);
      uint32_t bits;
#if RNG_PARTITIONABLE
      tf2x32(kk0,kk1,0u,f,o0,o1);
      bits=o0^o1;
#else
      { uint32_t p=(f<65536u)?f:(f-65536u);
        tf2x32(kk0,kk1,p,p+65536u,o0,o1);
        bits=(f<65536u)?o0:o1; }
#endif
      float fl=__uint_as_float((bits>>9)|0x3f800000u)-1.0f;
      float u=fmaxf(1.17549435e-38f, fl+1.17549435e-38f);
      float g=-logf(-logf(u));
      pert=g+sc;
    }
    float bp=pert, bm=sc; int bn=myn, ba=tid;
    #pragma unroll
    for (int off=1; off<64; off<<=1){
      float op=__shfl_xor(bp,off); int on=__shfl_xor(bn,off); int oa=__shfl_xor(ba,off);
      float om=__shfl_xor(bm,off);
      if (op>bp || (op==bp && on<bn)){ bp=op; bn=on; ba=oa; }
      bm=fmaxf(bm,om);
    }
    float e_=(tid<cnt)?expf(sc-bm):0.f;
    #pragma unroll
    for (int off=1; off<64; off<<=1) e_+=__shfl_xor(e_,off);
    if ((tid&63)==0){
      int w=tid>>6;
      red[w]=bp; red[4+w]=bm; red[8+w]=e_;
      ictl[2+w]=bn; ictl[6+w]=ba;
    }
    __syncthreads();
    if (tid==0){
      float M=fmaxf(fmaxf(red[4],red[5]),fmaxf(red[6],red[7]));
      float S=0.f;
      #pragma unroll
      for (int w=0;w<4;++w){
        float ew=red[8+w];
        if (ew>0.f) S += ew*expf(red[4+w]-M);
      }
      float bp2=red[0]; int bn2=ictl[2], ba2=ictl[6];
      #pragma unroll
      for (int w=1;w<4;++w){
        float op=red[w]; int on=ictl[2+w];
        if (op>bp2 || (op==bp2 && on<bn2)){ bp2=op; bn2=on; ba2=ictl[6+w]; }
      }
      logp_acc += sc_s[ba2] - M - logf(S);
      out[b*256+t]=(float)bn2;
      ictl[1]=bn2;
      alive[ba2]=alive[cnt-1];
    }
    __syncthreads();
    cnt-=1;
    if (t<255){
      int bn=ictl[1];
      if (tid<128) x_s[c]=EncOuts[(size_t)(b*256+bn)*128+c];
      __syncthreads();
      GI_PARTIAL();
    }
  }
  if (tid==0) out[131072+b]=logp_acc;
}

__global__ void k_telemetry(float* __restrict__ out, int n, float val){
  int i=blockIdx.x*blockDim.x+threadIdx.x;
  if (i<n) out[i]=val;
}

// ---------------------------------------------------------------------------
extern "C" void kernel_launch(void* const* d_in, const int* in_sizes, int n_in,
                              void* d_out, int out_size, void* d_ws, size_t ws_size,
                              hipStream_t stream){
  const float* points  = (const float*)d_in[0];
  const float* fc_w    = (const float*)d_in[1];
  const float* fc_b    = (const float*)d_in[2];
  const float* enc_wih = (const float*)d_in[3];
  const float* enc_whh = (const float*)d_in[4];
  const float* enc_bih = (const float*)d_in[5];
  const float* enc_bhh = (const float*)d_in[6];
  const float* dec_wih = (const float*)d_in[7];
  const float* dec_whh = (const float*)d_in[8];
  const float* dec_bih = (const float*)d_in[9];
  const float* dec_bhh = (const float*)d_in[10];
  const float* w1      = (const float*)d_in[11];
  const float* w2      = (const float*)d_in[12];
  const float* vt      = (const float*)d_in[13];
  const float* sp_w    = (const float*)d_in[14];
  const float* sp_b    = (const float*)d_in[15];
  float* out = (float*)d_out;

  const size_t needEnc  = (size_t)131072*128*4;              // 64 MiB
  const size_t needFast = needEnc + (size_t)131072*384*4;    // 256 MiB
  if (ws_size < needEnc){
    k_telemetry<<<(out_size+255)/256,256,0,stream>>>(out, out_size, (float)(ws_size>>20));
    return;
  }
  float* EncOuts = (float*)d_ws;

  enc_fused<<<512,512,0,stream>>>(points, fc_w, fc_b, enc_wih, enc_whh,
                                  enc_bih, enc_bhh, EncOuts);

  if (ws_size >= needFast){
    float* DecGI = EncOuts + (size_t)131072*128;
    gemm_decgi<<<2048,384,0,stream>>>(EncOuts, dec_wih, dec_bih, DecGI);
    const int lds2 = D2_LDS_FLOATS*4;   // 146,656 B
    (void)hipFuncSetAttribute((const void*)dec_fused2,
                              hipFuncAttributeMaxDynamicSharedMemorySize, lds2);
    dec_fused2<<<512,512,lds2,stream>>>(EncOuts, DecGI, points,
        dec_wih, dec_whh, dec_bih, dec_bhh, w1, w2, vt, sp_w, sp_b, out);
  } else {
    const int ldsf = DEC_LDS_FLOATS*4;  // 162,944 B
    (void)hipFuncSetAttribute((const void*)dec_fused_fb,
                              hipFuncAttributeMaxDynamicSharedMemorySize, ldsf);
    dec_fused_fb<<<512,256,ldsf,stream>>>(EncOuts, points, dec_wih, dec_whh,
        dec_bih, dec_bhh, w1, w2, vt, sp_w, sp_b, out);
  }
}